// Round 6
// baseline (617.548 us; speedup 1.0000x reference)
//
#include <hip/hip_runtime.h>
#include <cstdint>
#include <cstddef>

#define NNODES 50000
#define TT 24
#define DYNF 16
#define STATF 8
#define HDIM 64
#define NEDGES 1600000

typedef __attribute__((ext_vector_type(8))) short bf16x8;
typedef __attribute__((ext_vector_type(4))) short bf16x4;
typedef __attribute__((ext_vector_type(4))) float f32x4;

__device__ __forceinline__ float fast_sigmoid(float x) {
    float e = __expf(-x);
    return __builtin_amdgcn_rcpf(1.f + e);
}
// robust fast tanh: no inf/inf NaN at extremes
__device__ __forceinline__ float fast_tanh(float x) {
    float e = __expf(2.f * x);
    return 1.f - 2.f * __builtin_amdgcn_rcpf(e + 1.f);
}
// fp32 -> bf16 with round-to-nearest-even
__device__ __forceinline__ short f2bf(float f) {
    unsigned u = __float_as_uint(f);
    u = (u + 0x7FFFu + ((u >> 16) & 1u)) >> 16;
    return (short)u;
}
__device__ __forceinline__ bf16x8 cvt8(const float* __restrict__ p) {
    bf16x8 r;
    #pragma unroll
    for (int i = 0; i < 8; ++i) r[i] = f2bf(p[i]);
    return r;
}
__device__ __forceinline__ bf16x8 zero8() {
    bf16x8 z;
    #pragma unroll
    for (int i = 0; i < 8; ++i) z[i] = 0;
    return z;
}

// ---------------------------------------------------------------------------
// MFMA GRU + fused W1 transform (unchanged — below top-5 at R5).
// ---------------------------------------------------------------------------
__global__ __launch_bounds__(256, 3) void gru_w1_kernel(
    const float* __restrict__ x_dyn, const float* __restrict__ x_stat,
    const float* __restrict__ Wih, const float* __restrict__ Whh,
    const float* __restrict__ bih, const float* __restrict__ bhh,
    const float* __restrict__ W1, float* __restrict__ t1)
{
    constexpr int S_H = 72;   // bf16 units per hbuf row: 144B (16B-aligned, 2-way banks)
    constexpr int S_X = 40;   // bf16 units per xbuf row: 80B
    __shared__ short hbuf[2][64 * S_H];   // [node][feature] bf16, double-buffered
    __shared__ short xbuf[2][64 * S_X];   // [node][k] bf16; k 16..31 zeroed

    const int tid = (int)threadIdx.x;
    const int lane = tid & 63;
    const int w = __builtin_amdgcn_readfirstlane(tid >> 6);  // wave 0..3
    const int col = lane & 15;
    const int quad = lane >> 4;
    const int node0 = (int)blockIdx.x * 64;

    bf16x8 Bh[3][2];
    bf16x8 Bx[3];
    #pragma unroll
    for (int g = 0; g < 3; ++g) {
        const int n = (w + g * 4) * 16 + col;   // gate row in [0,192)
        #pragma unroll
        for (int kt = 0; kt < 2; ++kt)
            Bh[g][kt] = cvt8(Whh + (size_t)n * HDIM + kt * 32 + quad * 8);
        Bx[g] = (quad < 2) ? cvt8(Wih + (size_t)n * DYNF + quad * 8) : zero8();
    }

    const int jg = w * 16 + col;                 // feature 0..63
    const float b_r  = bih[jg]        + bhh[jg];
    const float b_z  = bih[HDIM + jg] + bhh[HDIM + jg];
    const float b_xn = bih[2 * HDIM + jg];
    const float b_hn = bhh[2 * HDIM + jg];

    for (int i = tid; i < 64 * S_H; i += 256) hbuf[0][i] = 0;

    auto stage_x = [&](int t, int b) {
        const int nd = tid >> 2, c = tid & 3;
        int node = node0 + nd;
        if (node >= NNODES) node = 0;
        const float4 v = *reinterpret_cast<const float4*>(
            x_dyn + (size_t)node * (TT * DYNF) + t * DYNF + c * 4);
        bf16x4 sv; sv[0] = f2bf(v.x); sv[1] = f2bf(v.y);
        sv[2] = f2bf(v.z); sv[3] = f2bf(v.w);
        bf16x4 zz; zz[0] = 0; zz[1] = 0; zz[2] = 0; zz[3] = 0;
        *reinterpret_cast<bf16x4*>(&xbuf[b][nd * S_X + c * 4]) = sv;
        *reinterpret_cast<bf16x4*>(&xbuf[b][nd * S_X + 16 + c * 4]) = zz;
    };
    stage_x(0, 0);

    float hprev[4][4];
    #pragma unroll
    for (int mt = 0; mt < 4; ++mt)
        #pragma unroll
        for (int r = 0; r < 4; ++r) hprev[mt][r] = 0.f;

    for (int t = 0; t < TT; ++t) {
        const int rb = t & 1;
        __syncthreads();   // hbuf[rb], xbuf[rb] ready

        f32x4 accr[4], accz[4], accnh[4], accnx[4];
        #pragma unroll
        for (int mt = 0; mt < 4; ++mt) {
            const int nd = mt * 16 + col;   // A-frag: m = lane&15 within tile
            const bf16x8 a0 = *reinterpret_cast<const bf16x8*>(&hbuf[rb][nd * S_H + quad * 8]);
            const bf16x8 a1 = *reinterpret_cast<const bf16x8*>(&hbuf[rb][nd * S_H + 32 + quad * 8]);
            const bf16x8 ax = *reinterpret_cast<const bf16x8*>(&xbuf[rb][nd * S_X + quad * 8]);
            const f32x4 z4 = {0.f, 0.f, 0.f, 0.f};
            accr[mt]  = __builtin_amdgcn_mfma_f32_16x16x32_bf16(a0, Bh[0][0], z4, 0, 0, 0);
            accr[mt]  = __builtin_amdgcn_mfma_f32_16x16x32_bf16(a1, Bh[0][1], accr[mt], 0, 0, 0);
            accr[mt]  = __builtin_amdgcn_mfma_f32_16x16x32_bf16(ax, Bx[0],    accr[mt], 0, 0, 0);
            accz[mt]  = __builtin_amdgcn_mfma_f32_16x16x32_bf16(a0, Bh[1][0], z4, 0, 0, 0);
            accz[mt]  = __builtin_amdgcn_mfma_f32_16x16x32_bf16(a1, Bh[1][1], accz[mt], 0, 0, 0);
            accz[mt]  = __builtin_amdgcn_mfma_f32_16x16x32_bf16(ax, Bx[1],    accz[mt], 0, 0, 0);
            accnh[mt] = __builtin_amdgcn_mfma_f32_16x16x32_bf16(a0, Bh[2][0], z4, 0, 0, 0);
            accnh[mt] = __builtin_amdgcn_mfma_f32_16x16x32_bf16(a1, Bh[2][1], accnh[mt], 0, 0, 0);
            accnx[mt] = __builtin_amdgcn_mfma_f32_16x16x32_bf16(ax, Bx[2],    z4, 0, 0, 0);
        }

        if (t + 1 < TT) stage_x(t + 1, rb ^ 1);  // overlap with MFMA drain

        #pragma unroll
        for (int mt = 0; mt < 4; ++mt) {
            #pragma unroll
            for (int r = 0; r < 4; ++r) {
                const float R  = fast_sigmoid(accr[mt][r] + b_r);
                const float Z  = fast_sigmoid(accz[mt][r] + b_z);
                const float Nn = fast_tanh(accnx[mt][r] + b_xn + R * (accnh[mt][r] + b_hn));
                const float hn = (1.f - Z) * Nn + Z * hprev[mt][r];
                hprev[mt][r] = hn;
                hbuf[rb ^ 1][(mt * 16 + quad * 4 + r) * S_H + jg] = f2bf(hn);
            }
        }
    }
    __syncthreads();   // final h in hbuf[0]

    // ---- fused W1: t1 = [h | x_stat] @ W1 ----
    bf16x8 Bw0, Bw1, Bw2;
    #pragma unroll
    for (int j = 0; j < 8; ++j) {
        Bw0[j] = f2bf(W1[(size_t)(quad * 8 + j) * HDIM + jg]);
        Bw1[j] = f2bf(W1[(size_t)(32 + quad * 8 + j) * HDIM + jg]);
    }
    if (quad == 0) {
        #pragma unroll
        for (int j = 0; j < 8; ++j)
            Bw2[j] = f2bf(W1[(size_t)(HDIM + j) * HDIM + jg]);
    } else {
        Bw2 = zero8();
    }

    #pragma unroll
    for (int mt = 0; mt < 4; ++mt) {
        const int nd = mt * 16 + col;
        const bf16x8 a0 = *reinterpret_cast<const bf16x8*>(&hbuf[0][nd * S_H + quad * 8]);
        const bf16x8 a1 = *reinterpret_cast<const bf16x8*>(&hbuf[0][nd * S_H + 32 + quad * 8]);
        bf16x8 axs;
        if (quad == 0) {
            int node = node0 + nd;
            if (node >= NNODES) node = 0;
            axs = cvt8(x_stat + (size_t)node * STATF);
        } else {
            axs = zero8();
        }
        const f32x4 z4 = {0.f, 0.f, 0.f, 0.f};
        f32x4 aw;
        aw = __builtin_amdgcn_mfma_f32_16x16x32_bf16(a0, Bw0, z4, 0, 0, 0);
        aw = __builtin_amdgcn_mfma_f32_16x16x32_bf16(a1, Bw1, aw, 0, 0, 0);
        aw = __builtin_amdgcn_mfma_f32_16x16x32_bf16(axs, Bw2, aw, 0, 0, 0);
        #pragma unroll
        for (int r = 0; r < 4; ++r) {
            const int node = node0 + mt * 16 + quad * 4 + r;
            if (node < NNODES) t1[(size_t)node * HDIM + jg] = aw[r];
        }
    }
}

// ---------------------------------------------------------------------------
// CSR build phase 1: in-degree histogram (int atomics, L2-cheap).
// ---------------------------------------------------------------------------
__global__ __launch_bounds__(256) void hist_kernel(
    const int* __restrict__ dstv, int* __restrict__ deg)
{
    const int e = blockIdx.x * 256 + threadIdx.x;
    if (e < NEDGES) atomicAdd(&deg[dstv[e]], 1);
}

// ---------------------------------------------------------------------------
// CSR build phase 2: exclusive scan of deg[0..N) -> offs[0..N], cursor copy.
// Single block, 1024 threads = 16 waves; wave shuffle scan, 3 barriers/chunk.
// ---------------------------------------------------------------------------
__global__ __launch_bounds__(1024) void scan_kernel(
    const int* __restrict__ deg, int* __restrict__ offs, int* __restrict__ cursor)
{
    __shared__ int wsum[16];
    const int tid = (int)threadIdx.x;
    const int lane = tid & 63;
    const int wid = tid >> 6;
    int carry = 0;

    for (int base = 0; base < NNODES; base += 1024) {
        const int idx = base + tid;
        const int v = (idx < NNODES) ? deg[idx] : 0;
        // inclusive wave scan
        int incl = v;
        #pragma unroll
        for (int off = 1; off < 64; off <<= 1) {
            int t = __shfl_up(incl, off, 64);
            if (lane >= off) incl += t;
        }
        if (lane == 63) wsum[wid] = incl;
        __syncthreads();
        if (wid == 0 && lane < 16) {
            int s = wsum[lane];
            #pragma unroll
            for (int off = 1; off < 16; off <<= 1) {
                int t = __shfl_up(s, off, 16);
                if ((lane & 15) >= off) s += t;
            }
            wsum[lane] = s;   // inclusive over wave totals
        }
        __syncthreads();
        const int wbase = (wid == 0) ? 0 : wsum[wid - 1];
        const int excl = carry + wbase + incl - v;
        if (idx < NNODES) { offs[idx] = excl; cursor[idx] = excl; }
        carry += wsum[15];
        __syncthreads();   // protect wsum before next chunk overwrites
    }
    if (tid == 0) offs[NNODES] = carry;
}

// ---------------------------------------------------------------------------
// CSR build phase 3: slot fill. pos = cursor[dst]++; store packed (src, w)
// as ONE 8B int2 -> one dirty line per edge instead of two.
// ---------------------------------------------------------------------------
__global__ __launch_bounds__(256) void fill_kernel(
    const int* __restrict__ srcv, const int* __restrict__ dstv,
    const float* __restrict__ ew, int* __restrict__ cursor,
    int2* __restrict__ csr)
{
    const int e = blockIdx.x * 256 + threadIdx.x;
    if (e >= NEDGES) return;
    const int d = dstv[e];
    const int pos = atomicAdd(&cursor[d], 1);
    int2 pk;
    pk.x = srcv[e];
    pk.y = __float_as_int(ew[e]);
    csr[pos] = pk;
}

// ---------------------------------------------------------------------------
// Gather-reduce per dst node: one wave per node, lane = feature.
// Per edge: broadcast packed (src,w) load + coalesced 256B row gather
// (L2/L3-resident table), fp32 register accumulate. No atomics.
// ---------------------------------------------------------------------------
__global__ __launch_bounds__(256) void gather_kernel(
    const float* __restrict__ tsrc, const int* __restrict__ offs,
    const int2* __restrict__ csr, float* __restrict__ agg)
{
    const int node = blockIdx.x * 4 + (threadIdx.x >> 6);
    const int lane = threadIdx.x & 63;
    if (node >= NNODES) return;
    const int beg = offs[node];
    const int end = offs[node + 1];
    float acc = 0.f;
    int i = beg;
    for (; i + 4 <= end; i += 4) {   // 4 independent gathers in flight
        const int2 e0 = csr[i],     e1 = csr[i + 1];
        const int2 e2 = csr[i + 2], e3 = csr[i + 3];
        const float v0 = tsrc[(size_t)e0.x * HDIM + lane];
        const float v1 = tsrc[(size_t)e1.x * HDIM + lane];
        const float v2 = tsrc[(size_t)e2.x * HDIM + lane];
        const float v3 = tsrc[(size_t)e3.x * HDIM + lane];
        acc += __int_as_float(e0.y) * v0 + __int_as_float(e1.y) * v1
             + __int_as_float(e2.y) * v2 + __int_as_float(e3.y) * v3;
    }
    for (; i < end; ++i) {
        const int2 ee = csr[i];
        acc += __int_as_float(ee.y) * tsrc[(size_t)ee.x * HDIM + lane];
    }
    agg[(size_t)node * HDIM + lane] = acc;
}

// ---------------------------------------------------------------------------
// h = relu(agg + bias); out = h @ W   (64x64). 4 threads/node, 16 outs each.
// ---------------------------------------------------------------------------
__global__ __launch_bounds__(256) void transform_kernel(
    const float* __restrict__ agg, const float* __restrict__ bias,
    const float* __restrict__ W, float* __restrict__ out)
{
    const int nl = threadIdx.x & 63;
    const int p = __builtin_amdgcn_readfirstlane((int)(threadIdx.x >> 6));
    const int node = blockIdx.x * 64 + nl;
    if (node >= NNODES) return;

    float in[HDIM];
    const float* arow = agg + (size_t)node * HDIM;
    #pragma unroll
    for (int c = 0; c < 16; ++c) {
        float4 v = *reinterpret_cast<const float4*>(arow + c * 4);
        in[c*4+0] = fmaxf(v.x + bias[c*4+0], 0.f);
        in[c*4+1] = fmaxf(v.y + bias[c*4+1], 0.f);
        in[c*4+2] = fmaxf(v.z + bias[c*4+2], 0.f);
        in[c*4+3] = fmaxf(v.w + bias[c*4+3], 0.f);
    }
    float acc[16];
    #pragma unroll
    for (int jj = 0; jj < 16; ++jj) acc[jj] = 0.f;
    #pragma unroll
    for (int k = 0; k < HDIM; ++k) {
        #pragma unroll
        for (int jj = 0; jj < 16; ++jj)
            acc[jj] += in[k] * W[k * HDIM + p * 16 + jj];
    }
    #pragma unroll
    for (int jj = 0; jj < 16; ++jj)
        out[(size_t)node * HDIM + p * 16 + jj] = acc[jj];
}

// ---------------------------------------------------------------------------
// Heads: h2 = relu(agg2 + b2); aqi = h2.Wa + ba; pm = h2.Wp + bp
// ---------------------------------------------------------------------------
__global__ __launch_bounds__(256) void head_kernel(
    const float* __restrict__ agg2, const float* __restrict__ b2,
    const float* __restrict__ Wa, const float* __restrict__ ba,
    const float* __restrict__ Wp, const float* __restrict__ bp,
    float* __restrict__ out)
{
    const int node = blockIdx.x * 256 + threadIdx.x;
    if (node >= NNODES) return;
    const float* arow = agg2 + (size_t)node * HDIM;
    float sa = 0.f, sp = 0.f;
    #pragma unroll
    for (int c = 0; c < 16; ++c) {
        float4 v = *reinterpret_cast<const float4*>(arow + c * 4);
        float h0 = fmaxf(v.x + b2[c*4+0], 0.f);
        float h1 = fmaxf(v.y + b2[c*4+1], 0.f);
        float h2 = fmaxf(v.z + b2[c*4+2], 0.f);
        float h3 = fmaxf(v.w + b2[c*4+3], 0.f);
        sa += h0 * Wa[c*4+0] + h1 * Wa[c*4+1] + h2 * Wa[c*4+2] + h3 * Wa[c*4+3];
        sp += h0 * Wp[c*4+0] + h1 * Wp[c*4+1] + h2 * Wp[c*4+2] + h3 * Wp[c*4+3];
    }
    out[node] = sa + ba[0];
    out[NNODES + node] = sp + bp[0];
}

extern "C" void kernel_launch(void* const* d_in, const int* in_sizes, int n_in,
                              void* d_out, int out_size, void* d_ws, size_t ws_size,
                              hipStream_t stream)
{
    const float* x_dyn  = (const float*)d_in[0];
    const float* x_stat = (const float*)d_in[1];
    const int*   eidx   = (const int*)  d_in[2];
    const float* ew     = (const float*)d_in[3];
    const float* Wih    = (const float*)d_in[4];
    const float* Whh    = (const float*)d_in[5];
    const float* bih    = (const float*)d_in[6];
    const float* bhh    = (const float*)d_in[7];
    const float* W1     = (const float*)d_in[8];
    const float* b1     = (const float*)d_in[9];
    const float* W2     = (const float*)d_in[10];
    const float* b2     = (const float*)d_in[11];
    const float* Wa     = (const float*)d_in[12];
    const float* ba     = (const float*)d_in[13];
    const float* Wp     = (const float*)d_in[14];
    const float* bp     = (const float*)d_in[15];

    const int* srcv = eidx;
    const int* dstv = eidx + NEDGES;

    // workspace layout (4B units)
    const size_t NH = (size_t)NNODES * HDIM;    // 3.2M
    float* ws   = (float*)d_ws;
    float* t1   = ws;                 // [NH]
    float* agg1 = ws + NH;            // [NH]
    float* t2   = ws + 2 * NH;        // [NH]
    float* agg2 = ws + 3 * NH;        // [NH]
    int*   deg    = (int*)(ws + 4 * NH);              // [NNODES]
    int*   offs   = deg + NNODES;                     // [NNODES+1]
    int*   cursor = offs + NNODES + 1;                // [NNODES+1 pad -> keep int2 aligned]
    int2*  csr    = (int2*)(cursor + NNODES + 1);     // [NEDGES] packed (src, w)

    dim3 blk(256);

    // ---- GRU + W1 (longest independent work first) ----
    gru_w1_kernel<<<dim3((NNODES + 63) / 64), blk, 0, stream>>>(
        x_dyn, x_stat, Wih, Whh, bih, bhh, W1, t1);

    // ---- CSR build (once, reused by both layers) ----
    hipMemsetAsync(deg, 0, (size_t)NNODES * sizeof(int), stream);
    hist_kernel<<<dim3((NEDGES + 255) / 256), blk, 0, stream>>>(dstv, deg);
    scan_kernel<<<dim3(1), dim3(1024), 0, stream>>>(deg, offs, cursor);
    fill_kernel<<<dim3((NEDGES + 255) / 256), blk, 0, stream>>>(
        srcv, dstv, ew, cursor, csr);

    // ---- layer 1 ----
    gather_kernel<<<dim3((NNODES + 3) / 4), blk, 0, stream>>>(t1, offs, csr, agg1);
    transform_kernel<<<dim3((NNODES + 63) / 64), blk, 0, stream>>>(agg1, b1, W2, t2);

    // ---- layer 2 ----
    gather_kernel<<<dim3((NNODES + 3) / 4), blk, 0, stream>>>(t2, offs, csr, agg2);
    head_kernel<<<dim3((NNODES + 255) / 256), blk, 0, stream>>>(
        agg2, b2, Wa, ba, Wp, bp, (float*)d_out);
}

// Round 7
// 571.024 us; speedup vs baseline: 1.0815x; 1.0815x over previous
//
#include <hip/hip_runtime.h>
#include <cstdint>
#include <cstddef>

#define NNODES 50000
#define TT 24
#define DYNF 16
#define STATF 8
#define HDIM 64
#define NEDGES 1600000
#define NB 32   // nodes per GRU block

typedef __attribute__((ext_vector_type(8))) short bf16x8;
typedef __attribute__((ext_vector_type(4))) float f32x4;

__device__ __forceinline__ float fast_sigmoid(float x) {
    float e = __expf(-x);
    return __builtin_amdgcn_rcpf(1.f + e);
}
// robust fast tanh: no inf/inf NaN at extremes
__device__ __forceinline__ float fast_tanh(float x) {
    float e = __expf(2.f * x);
    return 1.f - 2.f * __builtin_amdgcn_rcpf(e + 1.f);
}
// fp32 -> bf16 with round-to-nearest-even
__device__ __forceinline__ unsigned short f2bf(float f) {
    unsigned u = __float_as_uint(f);
    u = (u + 0x7FFFu + ((u >> 16) & 1u)) >> 16;
    return (unsigned short)u;
}
__device__ __forceinline__ float bf2f(unsigned short s) {
    return __uint_as_float((unsigned)s << 16);
}
__device__ __forceinline__ bf16x8 cvt8(const float* __restrict__ p) {
    bf16x8 r;
    #pragma unroll
    for (int i = 0; i < 8; ++i) r[i] = (short)f2bf(p[i]);
    return r;
}
__device__ __forceinline__ bf16x8 zero8() {
    bf16x8 z;
    #pragma unroll
    for (int i = 0; i < 8; ++i) z[i] = 0;
    return z;
}

// ---------------------------------------------------------------------------
// MFMA GRU + fused W1 transform. Block = 32 nodes x 4 waves (grid 1563 ->
// ~6 blocks/CU co-resident, vs 3 at 64-node blocks: hides step latency).
// Per step: G(32x192) = [h|x_t](32x96) @ B(96x192), 16x16x32 bf16 MFMA.
// Wave w owns gate N-tiles {w, w+4, w+8}; C/D: col=gate-feature, row=node.
// h_prev carried in fp32 regs; h round-trips LDS in bf16 (double-buffered).
// t1 output is bf16 (halves gather-side row bytes).
// ---------------------------------------------------------------------------
__global__ __launch_bounds__(256, 4) void gru_w1_kernel(
    const float* __restrict__ x_dyn, const float* __restrict__ x_stat,
    const float* __restrict__ Wih, const float* __restrict__ Whh,
    const float* __restrict__ bih, const float* __restrict__ bhh,
    const float* __restrict__ W1, unsigned short* __restrict__ t1)
{
    constexpr int S_H = 72;   // bf16 units per hbuf row (144B: 16B-aligned)
    constexpr int S_X = 40;   // bf16 units per xbuf row
    __shared__ short hbuf[2][NB * S_H];   // [node][feature] bf16, dbuf (9.2KB)
    __shared__ short xbuf[2][NB * S_X];   // [node][k] bf16; k 16..31 zeroed (5.1KB)

    const int tid = (int)threadIdx.x;
    const int lane = tid & 63;
    const int w = __builtin_amdgcn_readfirstlane(tid >> 6);  // wave 0..3
    const int col = lane & 15;
    const int quad = lane >> 4;
    const int node0 = (int)blockIdx.x * NB;

    bf16x8 Bh[3][2];
    bf16x8 Bx[3];
    #pragma unroll
    for (int g = 0; g < 3; ++g) {
        const int n = (w + g * 4) * 16 + col;   // gate row in [0,192)
        #pragma unroll
        for (int kt = 0; kt < 2; ++kt)
            Bh[g][kt] = cvt8(Whh + (size_t)n * HDIM + kt * 32 + quad * 8);
        Bx[g] = (quad < 2) ? cvt8(Wih + (size_t)n * DYNF + quad * 8) : zero8();
    }

    const int jg = w * 16 + col;                 // feature 0..63
    const float b_r  = bih[jg]        + bhh[jg];
    const float b_z  = bih[HDIM + jg] + bhh[HDIM + jg];
    const float b_xn = bih[2 * HDIM + jg];
    const float b_hn = bhh[2 * HDIM + jg];

    for (int i = tid; i < NB * S_H; i += 256) hbuf[0][i] = 0;

    // stage x_t: 32 nodes x 8 float2 chunks = 256 tasks
    auto stage_x = [&](int t, int b) {
        const int nd = tid >> 3, c = tid & 7;
        int node = node0 + nd;
        if (node >= NNODES) node = 0;
        const float2 v = *reinterpret_cast<const float2*>(
            x_dyn + (size_t)node * (TT * DYNF) + t * DYNF + c * 2);
        unsigned pk = (unsigned)f2bf(v.x) | ((unsigned)f2bf(v.y) << 16);
        *reinterpret_cast<unsigned*>(&xbuf[b][nd * S_X + c * 2]) = pk;
        *reinterpret_cast<unsigned*>(&xbuf[b][nd * S_X + 16 + c * 2]) = 0u;
    };
    stage_x(0, 0);

    float hprev[2][4];
    #pragma unroll
    for (int mt = 0; mt < 2; ++mt)
        #pragma unroll
        for (int r = 0; r < 4; ++r) hprev[mt][r] = 0.f;

    for (int t = 0; t < TT; ++t) {
        const int rb = t & 1;
        __syncthreads();   // hbuf[rb], xbuf[rb] ready

        f32x4 accr[2], accz[2], accnh[2], accnx[2];
        #pragma unroll
        for (int mt = 0; mt < 2; ++mt) {
            const int nd = mt * 16 + col;   // A-frag: m = lane&15 within tile
            const bf16x8 a0 = *reinterpret_cast<const bf16x8*>(&hbuf[rb][nd * S_H + quad * 8]);
            const bf16x8 a1 = *reinterpret_cast<const bf16x8*>(&hbuf[rb][nd * S_H + 32 + quad * 8]);
            const bf16x8 ax = *reinterpret_cast<const bf16x8*>(&xbuf[rb][nd * S_X + quad * 8]);
            const f32x4 z4 = {0.f, 0.f, 0.f, 0.f};
            accr[mt]  = __builtin_amdgcn_mfma_f32_16x16x32_bf16(a0, Bh[0][0], z4, 0, 0, 0);
            accr[mt]  = __builtin_amdgcn_mfma_f32_16x16x32_bf16(a1, Bh[0][1], accr[mt], 0, 0, 0);
            accr[mt]  = __builtin_amdgcn_mfma_f32_16x16x32_bf16(ax, Bx[0],    accr[mt], 0, 0, 0);
            accz[mt]  = __builtin_amdgcn_mfma_f32_16x16x32_bf16(a0, Bh[1][0], z4, 0, 0, 0);
            accz[mt]  = __builtin_amdgcn_mfma_f32_16x16x32_bf16(a1, Bh[1][1], accz[mt], 0, 0, 0);
            accz[mt]  = __builtin_amdgcn_mfma_f32_16x16x32_bf16(ax, Bx[1],    accz[mt], 0, 0, 0);
            accnh[mt] = __builtin_amdgcn_mfma_f32_16x16x32_bf16(a0, Bh[2][0], z4, 0, 0, 0);
            accnh[mt] = __builtin_amdgcn_mfma_f32_16x16x32_bf16(a1, Bh[2][1], accnh[mt], 0, 0, 0);
            accnx[mt] = __builtin_amdgcn_mfma_f32_16x16x32_bf16(ax, Bx[2],    z4, 0, 0, 0);
        }

        if (t + 1 < TT) stage_x(t + 1, rb ^ 1);  // overlap with MFMA drain

        #pragma unroll
        for (int mt = 0; mt < 2; ++mt) {
            #pragma unroll
            for (int r = 0; r < 4; ++r) {
                const float R  = fast_sigmoid(accr[mt][r] + b_r);
                const float Z  = fast_sigmoid(accz[mt][r] + b_z);
                const float Nn = fast_tanh(accnx[mt][r] + b_xn + R * (accnh[mt][r] + b_hn));
                const float hn = Nn + Z * (hprev[mt][r] - Nn);
                hprev[mt][r] = hn;
                hbuf[rb ^ 1][(mt * 16 + quad * 4 + r) * S_H + jg] = (short)f2bf(hn);
            }
        }
    }
    __syncthreads();   // final h in hbuf[0]

    // ---- fused W1: t1 = [h | x_stat] @ W1 (bf16 out) ----
    bf16x8 Bw0, Bw1, Bw2;
    #pragma unroll
    for (int j = 0; j < 8; ++j) {
        Bw0[j] = (short)f2bf(W1[(size_t)(quad * 8 + j) * HDIM + jg]);
        Bw1[j] = (short)f2bf(W1[(size_t)(32 + quad * 8 + j) * HDIM + jg]);
    }
    if (quad == 0) {
        #pragma unroll
        for (int j = 0; j < 8; ++j)
            Bw2[j] = (short)f2bf(W1[(size_t)(HDIM + j) * HDIM + jg]);
    } else {
        Bw2 = zero8();
    }

    #pragma unroll
    for (int mt = 0; mt < 2; ++mt) {
        const int nd = mt * 16 + col;
        const bf16x8 a0 = *reinterpret_cast<const bf16x8*>(&hbuf[0][nd * S_H + quad * 8]);
        const bf16x8 a1 = *reinterpret_cast<const bf16x8*>(&hbuf[0][nd * S_H + 32 + quad * 8]);
        bf16x8 axs;
        if (quad == 0) {
            int node = node0 + nd;
            if (node >= NNODES) node = 0;
            axs = cvt8(x_stat + (size_t)node * STATF);
        } else {
            axs = zero8();
        }
        const f32x4 z4 = {0.f, 0.f, 0.f, 0.f};
        f32x4 aw;
        aw = __builtin_amdgcn_mfma_f32_16x16x32_bf16(a0, Bw0, z4, 0, 0, 0);
        aw = __builtin_amdgcn_mfma_f32_16x16x32_bf16(a1, Bw1, aw, 0, 0, 0);
        aw = __builtin_amdgcn_mfma_f32_16x16x32_bf16(axs, Bw2, aw, 0, 0, 0);
        #pragma unroll
        for (int r = 0; r < 4; ++r) {
            const int node = node0 + mt * 16 + quad * 4 + r;
            if (node < NNODES) t1[(size_t)node * HDIM + jg] = f2bf(aw[r]);
        }
    }
}

// ---------------------------------------------------------------------------
// CSR build phase 1: in-degree histogram (int atomics, L2-cheap).
// ---------------------------------------------------------------------------
__global__ __launch_bounds__(256) void hist_kernel(
    const int* __restrict__ dstv, int* __restrict__ deg)
{
    const int e = blockIdx.x * 256 + threadIdx.x;
    if (e < NEDGES) atomicAdd(&deg[dstv[e]], 1);
}

// ---------------------------------------------------------------------------
// CSR build phase 2: exclusive scan of deg -> offs, cursor copy.
// ---------------------------------------------------------------------------
__global__ __launch_bounds__(1024) void scan_kernel(
    const int* __restrict__ deg, int* __restrict__ offs, int* __restrict__ cursor)
{
    __shared__ int wsum[16];
    const int tid = (int)threadIdx.x;
    const int lane = tid & 63;
    const int wid = tid >> 6;
    int carry = 0;

    for (int base = 0; base < NNODES; base += 1024) {
        const int idx = base + tid;
        const int v = (idx < NNODES) ? deg[idx] : 0;
        int incl = v;
        #pragma unroll
        for (int off = 1; off < 64; off <<= 1) {
            int t = __shfl_up(incl, off, 64);
            if (lane >= off) incl += t;
        }
        if (lane == 63) wsum[wid] = incl;
        __syncthreads();
        if (wid == 0 && lane < 16) {
            int s = wsum[lane];
            #pragma unroll
            for (int off = 1; off < 16; off <<= 1) {
                int t = __shfl_up(s, off, 16);
                if ((lane & 15) >= off) s += t;
            }
            wsum[lane] = s;
        }
        __syncthreads();
        const int wbase = (wid == 0) ? 0 : wsum[wid - 1];
        const int excl = carry + wbase + incl - v;
        if (idx < NNODES) { offs[idx] = excl; cursor[idx] = excl; }
        carry += wsum[15];
        __syncthreads();
    }
    if (tid == 0) offs[NNODES] = carry;
}

// ---------------------------------------------------------------------------
// CSR build phase 3: slot fill. ONE 4B store per edge:
// pack = src (low 16, NNODES<65536) | bf16(weight) << 16.
// ---------------------------------------------------------------------------
__global__ __launch_bounds__(256) void fill_kernel(
    const int* __restrict__ srcv, const int* __restrict__ dstv,
    const float* __restrict__ ew, int* __restrict__ cursor,
    unsigned* __restrict__ csr)
{
    const int e = blockIdx.x * 256 + threadIdx.x;
    if (e >= NEDGES) return;
    const int d = dstv[e];
    const int pos = atomicAdd(&cursor[d], 1);
    csr[pos] = (unsigned)srcv[e] | ((unsigned)f2bf(ew[e]) << 16);
}

// ---------------------------------------------------------------------------
// Gather-reduce per dst node: one wave per node, lane = feature.
// Per edge: 4B packed (src,w) broadcast load + coalesced 128B bf16 row gather
// (6.4MB table, L2-resident). Hi-16 bits of pack ARE the fp32 weight pattern.
// ---------------------------------------------------------------------------
__global__ __launch_bounds__(256) void gather_kernel(
    const unsigned short* __restrict__ tsrc, const int* __restrict__ offs,
    const unsigned* __restrict__ csr, float* __restrict__ agg)
{
    const int node = blockIdx.x * 4 + (threadIdx.x >> 6);
    const int lane = threadIdx.x & 63;
    if (node >= NNODES) return;
    const int beg = offs[node];
    const int end = offs[node + 1];
    float acc = 0.f;
    int i = beg;
    for (; i + 4 <= end; i += 4) {   // 4 independent gathers in flight
        const unsigned p0 = csr[i],     p1 = csr[i + 1];
        const unsigned p2 = csr[i + 2], p3 = csr[i + 3];
        const float v0 = bf2f(tsrc[(size_t)(p0 & 0xFFFFu) * HDIM + lane]);
        const float v1 = bf2f(tsrc[(size_t)(p1 & 0xFFFFu) * HDIM + lane]);
        const float v2 = bf2f(tsrc[(size_t)(p2 & 0xFFFFu) * HDIM + lane]);
        const float v3 = bf2f(tsrc[(size_t)(p3 & 0xFFFFu) * HDIM + lane]);
        acc += __uint_as_float(p0 & 0xFFFF0000u) * v0
             + __uint_as_float(p1 & 0xFFFF0000u) * v1
             + __uint_as_float(p2 & 0xFFFF0000u) * v2
             + __uint_as_float(p3 & 0xFFFF0000u) * v3;
    }
    for (; i < end; ++i) {
        const unsigned p = csr[i];
        acc += __uint_as_float(p & 0xFFFF0000u)
             * bf2f(tsrc[(size_t)(p & 0xFFFFu) * HDIM + lane]);
    }
    agg[(size_t)node * HDIM + lane] = acc;
}

// ---------------------------------------------------------------------------
// h = relu(agg + bias); out = h @ W (64x64), bf16 out. 4 threads/node.
// ---------------------------------------------------------------------------
__global__ __launch_bounds__(256) void transform_kernel(
    const float* __restrict__ agg, const float* __restrict__ bias,
    const float* __restrict__ W, unsigned short* __restrict__ out)
{
    const int nl = threadIdx.x & 63;
    const int p = __builtin_amdgcn_readfirstlane((int)(threadIdx.x >> 6));
    const int node = blockIdx.x * 64 + nl;
    if (node >= NNODES) return;

    float in[HDIM];
    const float* arow = agg + (size_t)node * HDIM;
    #pragma unroll
    for (int c = 0; c < 16; ++c) {
        float4 v = *reinterpret_cast<const float4*>(arow + c * 4);
        in[c*4+0] = fmaxf(v.x + bias[c*4+0], 0.f);
        in[c*4+1] = fmaxf(v.y + bias[c*4+1], 0.f);
        in[c*4+2] = fmaxf(v.z + bias[c*4+2], 0.f);
        in[c*4+3] = fmaxf(v.w + bias[c*4+3], 0.f);
    }
    float acc[16];
    #pragma unroll
    for (int jj = 0; jj < 16; ++jj) acc[jj] = 0.f;
    #pragma unroll
    for (int k = 0; k < HDIM; ++k) {
        #pragma unroll
        for (int jj = 0; jj < 16; ++jj)
            acc[jj] += in[k] * W[k * HDIM + p * 16 + jj];
    }
    bf16x8 o0, o1;
    #pragma unroll
    for (int jj = 0; jj < 8; ++jj) {
        o0[jj] = (short)f2bf(acc[jj]);
        o1[jj] = (short)f2bf(acc[jj + 8]);
    }
    unsigned short* orow = out + (size_t)node * HDIM + p * 16;
    *reinterpret_cast<bf16x8*>(orow) = o0;
    *reinterpret_cast<bf16x8*>(orow + 8) = o1;
}

// ---------------------------------------------------------------------------
// Heads: h2 = relu(agg2 + b2); aqi = h2.Wa + ba; pm = h2.Wp + bp
// ---------------------------------------------------------------------------
__global__ __launch_bounds__(256) void head_kernel(
    const float* __restrict__ agg2, const float* __restrict__ b2,
    const float* __restrict__ Wa, const float* __restrict__ ba,
    const float* __restrict__ Wp, const float* __restrict__ bp,
    float* __restrict__ out)
{
    const int node = blockIdx.x * 256 + threadIdx.x;
    if (node >= NNODES) return;
    const float* arow = agg2 + (size_t)node * HDIM;
    float sa = 0.f, sp = 0.f;
    #pragma unroll
    for (int c = 0; c < 16; ++c) {
        float4 v = *reinterpret_cast<const float4*>(arow + c * 4);
        float h0 = fmaxf(v.x + b2[c*4+0], 0.f);
        float h1 = fmaxf(v.y + b2[c*4+1], 0.f);
        float h2 = fmaxf(v.z + b2[c*4+2], 0.f);
        float h3 = fmaxf(v.w + b2[c*4+3], 0.f);
        sa += h0 * Wa[c*4+0] + h1 * Wa[c*4+1] + h2 * Wa[c*4+2] + h3 * Wa[c*4+3];
        sp += h0 * Wp[c*4+0] + h1 * Wp[c*4+1] + h2 * Wp[c*4+2] + h3 * Wp[c*4+3];
    }
    out[node] = sa + ba[0];
    out[NNODES + node] = sp + bp[0];
}

extern "C" void kernel_launch(void* const* d_in, const int* in_sizes, int n_in,
                              void* d_out, int out_size, void* d_ws, size_t ws_size,
                              hipStream_t stream)
{
    const float* x_dyn  = (const float*)d_in[0];
    const float* x_stat = (const float*)d_in[1];
    const int*   eidx   = (const int*)  d_in[2];
    const float* ew     = (const float*)d_in[3];
    const float* Wih    = (const float*)d_in[4];
    const float* Whh    = (const float*)d_in[5];
    const float* bih    = (const float*)d_in[6];
    const float* bhh    = (const float*)d_in[7];
    const float* W1     = (const float*)d_in[8];
    const float* b1     = (const float*)d_in[9];
    const float* W2     = (const float*)d_in[10];
    const float* b2     = (const float*)d_in[11];
    const float* Wa     = (const float*)d_in[12];
    const float* ba     = (const float*)d_in[13];
    const float* Wp     = (const float*)d_in[14];
    const float* bp     = (const float*)d_in[15];

    const int* srcv = eidx;
    const int* dstv = eidx + NEDGES;

    // workspace layout (4B units)
    const size_t NH = (size_t)NNODES * HDIM;    // 3.2M elements
    float* ws   = (float*)d_ws;
    unsigned short* t1 = (unsigned short*)ws;                 // [NH] bf16
    unsigned short* t2 = (unsigned short*)(ws + NH / 2);      // [NH] bf16
    float* agg1 = ws + NH;            // [NH] fp32
    float* agg2 = ws + 2 * NH;        // [NH] fp32
    int*   deg    = (int*)(ws + 3 * NH);              // [NNODES]
    int*   offs   = deg + NNODES;                     // [NNODES+1]
    int*   cursor = offs + NNODES + 1;                // [NNODES]
    unsigned* csr = (unsigned*)(cursor + NNODES);     // [NEDGES] packed (src|w)

    dim3 blk(256);

    // ---- GRU + W1 (longest independent work first) ----
    gru_w1_kernel<<<dim3((NNODES + NB - 1) / NB), blk, 0, stream>>>(
        x_dyn, x_stat, Wih, Whh, bih, bhh, W1, t1);

    // ---- CSR build (once, reused by both layers) ----
    hipMemsetAsync(deg, 0, (size_t)NNODES * sizeof(int), stream);
    hist_kernel<<<dim3((NEDGES + 255) / 256), blk, 0, stream>>>(dstv, deg);
    scan_kernel<<<dim3(1), dim3(1024), 0, stream>>>(deg, offs, cursor);
    fill_kernel<<<dim3((NEDGES + 255) / 256), blk, 0, stream>>>(
        srcv, dstv, ew, cursor, csr);

    // ---- layer 1 ----
    gather_kernel<<<dim3((NNODES + 3) / 4), blk, 0, stream>>>(t1, offs, csr, agg1);
    transform_kernel<<<dim3((NNODES + 63) / 64), blk, 0, stream>>>(agg1, b1, W2, t2);

    // ---- layer 2 ----
    gather_kernel<<<dim3((NNODES + 3) / 4), blk, 0, stream>>>(t2, offs, csr, agg2);
    head_kernel<<<dim3((NNODES + 255) / 256), blk, 0, stream>>>(
        agg2, b2, Wa, ba, Wp, bp, (float*)d_out);
}

// Round 8
// 529.457 us; speedup vs baseline: 1.1664x; 1.0785x over previous
//
#include <hip/hip_runtime.h>
#include <cstdint>
#include <cstddef>

#define NNODES 50000
#define TT 24
#define DYNF 16
#define STATF 8
#define HDIM 64
#define NEDGES 1600000
#define NB 32   // nodes per GRU block

typedef __attribute__((ext_vector_type(8))) short bf16x8;
typedef __attribute__((ext_vector_type(4))) float f32x4;

__device__ __forceinline__ float fast_sigmoid(float x) {
    float e = __expf(-x);
    return __builtin_amdgcn_rcpf(1.f + e);
}
// robust fast tanh: no inf/inf NaN at extremes
__device__ __forceinline__ float fast_tanh(float x) {
    float e = __expf(2.f * x);
    return 1.f - 2.f * __builtin_amdgcn_rcpf(e + 1.f);
}
// fp32 -> bf16 with round-to-nearest-even
__device__ __forceinline__ unsigned short f2bf(float f) {
    unsigned u = __float_as_uint(f);
    u = (u + 0x7FFFu + ((u >> 16) & 1u)) >> 16;
    return (unsigned short)u;
}
__device__ __forceinline__ float bf2f(unsigned short s) {
    return __uint_as_float((unsigned)s << 16);
}
__device__ __forceinline__ bf16x8 cvt8(const float* __restrict__ p) {
    bf16x8 r;
    #pragma unroll
    for (int i = 0; i < 8; ++i) r[i] = (short)f2bf(p[i]);
    return r;
}
__device__ __forceinline__ bf16x8 zero8() {
    bf16x8 z;
    #pragma unroll
    for (int i = 0; i < 8; ++i) z[i] = 0;
    return z;
}

// ---------------------------------------------------------------------------
// MFMA GRU + fused W1 transform. Block = 32 nodes x 4 waves.
// (unchanged from R7 — below top-5)
// ---------------------------------------------------------------------------
__global__ __launch_bounds__(256, 4) void gru_w1_kernel(
    const float* __restrict__ x_dyn, const float* __restrict__ x_stat,
    const float* __restrict__ Wih, const float* __restrict__ Whh,
    const float* __restrict__ bih, const float* __restrict__ bhh,
    const float* __restrict__ W1, unsigned short* __restrict__ t1)
{
    constexpr int S_H = 72;   // bf16 units per hbuf row (144B: 16B-aligned)
    constexpr int S_X = 40;   // bf16 units per xbuf row
    __shared__ short hbuf[2][NB * S_H];   // [node][feature] bf16, dbuf
    __shared__ short xbuf[2][NB * S_X];   // [node][k] bf16; k 16..31 zeroed

    const int tid = (int)threadIdx.x;
    const int lane = tid & 63;
    const int w = __builtin_amdgcn_readfirstlane(tid >> 6);  // wave 0..3
    const int col = lane & 15;
    const int quad = lane >> 4;
    const int node0 = (int)blockIdx.x * NB;

    bf16x8 Bh[3][2];
    bf16x8 Bx[3];
    #pragma unroll
    for (int g = 0; g < 3; ++g) {
        const int n = (w + g * 4) * 16 + col;   // gate row in [0,192)
        #pragma unroll
        for (int kt = 0; kt < 2; ++kt)
            Bh[g][kt] = cvt8(Whh + (size_t)n * HDIM + kt * 32 + quad * 8);
        Bx[g] = (quad < 2) ? cvt8(Wih + (size_t)n * DYNF + quad * 8) : zero8();
    }

    const int jg = w * 16 + col;                 // feature 0..63
    const float b_r  = bih[jg]        + bhh[jg];
    const float b_z  = bih[HDIM + jg] + bhh[HDIM + jg];
    const float b_xn = bih[2 * HDIM + jg];
    const float b_hn = bhh[2 * HDIM + jg];

    for (int i = tid; i < NB * S_H; i += 256) hbuf[0][i] = 0;

    // stage x_t: 32 nodes x 8 float2 chunks = 256 tasks
    auto stage_x = [&](int t, int b) {
        const int nd = tid >> 3, c = tid & 7;
        int node = node0 + nd;
        if (node >= NNODES) node = 0;
        const float2 v = *reinterpret_cast<const float2*>(
            x_dyn + (size_t)node * (TT * DYNF) + t * DYNF + c * 2);
        unsigned pk = (unsigned)f2bf(v.x) | ((unsigned)f2bf(v.y) << 16);
        *reinterpret_cast<unsigned*>(&xbuf[b][nd * S_X + c * 2]) = pk;
        *reinterpret_cast<unsigned*>(&xbuf[b][nd * S_X + 16 + c * 2]) = 0u;
    };
    stage_x(0, 0);

    float hprev[2][4];
    #pragma unroll
    for (int mt = 0; mt < 2; ++mt)
        #pragma unroll
        for (int r = 0; r < 4; ++r) hprev[mt][r] = 0.f;

    for (int t = 0; t < TT; ++t) {
        const int rb = t & 1;
        __syncthreads();   // hbuf[rb], xbuf[rb] ready

        f32x4 accr[2], accz[2], accnh[2], accnx[2];
        #pragma unroll
        for (int mt = 0; mt < 2; ++mt) {
            const int nd = mt * 16 + col;   // A-frag: m = lane&15 within tile
            const bf16x8 a0 = *reinterpret_cast<const bf16x8*>(&hbuf[rb][nd * S_H + quad * 8]);
            const bf16x8 a1 = *reinterpret_cast<const bf16x8*>(&hbuf[rb][nd * S_H + 32 + quad * 8]);
            const bf16x8 ax = *reinterpret_cast<const bf16x8*>(&xbuf[rb][nd * S_X + quad * 8]);
            const f32x4 z4 = {0.f, 0.f, 0.f, 0.f};
            accr[mt]  = __builtin_amdgcn_mfma_f32_16x16x32_bf16(a0, Bh[0][0], z4, 0, 0, 0);
            accr[mt]  = __builtin_amdgcn_mfma_f32_16x16x32_bf16(a1, Bh[0][1], accr[mt], 0, 0, 0);
            accr[mt]  = __builtin_amdgcn_mfma_f32_16x16x32_bf16(ax, Bx[0],    accr[mt], 0, 0, 0);
            accz[mt]  = __builtin_amdgcn_mfma_f32_16x16x32_bf16(a0, Bh[1][0], z4, 0, 0, 0);
            accz[mt]  = __builtin_amdgcn_mfma_f32_16x16x32_bf16(a1, Bh[1][1], accz[mt], 0, 0, 0);
            accz[mt]  = __builtin_amdgcn_mfma_f32_16x16x32_bf16(ax, Bx[1],    accz[mt], 0, 0, 0);
            accnh[mt] = __builtin_amdgcn_mfma_f32_16x16x32_bf16(a0, Bh[2][0], z4, 0, 0, 0);
            accnh[mt] = __builtin_amdgcn_mfma_f32_16x16x32_bf16(a1, Bh[2][1], accnh[mt], 0, 0, 0);
            accnx[mt] = __builtin_amdgcn_mfma_f32_16x16x32_bf16(ax, Bx[2],    z4, 0, 0, 0);
        }

        if (t + 1 < TT) stage_x(t + 1, rb ^ 1);  // overlap with MFMA drain

        #pragma unroll
        for (int mt = 0; mt < 2; ++mt) {
            #pragma unroll
            for (int r = 0; r < 4; ++r) {
                const float R  = fast_sigmoid(accr[mt][r] + b_r);
                const float Z  = fast_sigmoid(accz[mt][r] + b_z);
                const float Nn = fast_tanh(accnx[mt][r] + b_xn + R * (accnh[mt][r] + b_hn));
                const float hn = Nn + Z * (hprev[mt][r] - Nn);
                hprev[mt][r] = hn;
                hbuf[rb ^ 1][(mt * 16 + quad * 4 + r) * S_H + jg] = (short)f2bf(hn);
            }
        }
    }
    __syncthreads();   // final h in hbuf[0]

    // ---- fused W1: t1 = [h | x_stat] @ W1 (bf16 out) ----
    bf16x8 Bw0, Bw1, Bw2;
    #pragma unroll
    for (int j = 0; j < 8; ++j) {
        Bw0[j] = (short)f2bf(W1[(size_t)(quad * 8 + j) * HDIM + jg]);
        Bw1[j] = (short)f2bf(W1[(size_t)(32 + quad * 8 + j) * HDIM + jg]);
    }
    if (quad == 0) {
        #pragma unroll
        for (int j = 0; j < 8; ++j)
            Bw2[j] = (short)f2bf(W1[(size_t)(HDIM + j) * HDIM + jg]);
    } else {
        Bw2 = zero8();
    }

    #pragma unroll
    for (int mt = 0; mt < 2; ++mt) {
        const int nd = mt * 16 + col;
        const bf16x8 a0 = *reinterpret_cast<const bf16x8*>(&hbuf[0][nd * S_H + quad * 8]);
        const bf16x8 a1 = *reinterpret_cast<const bf16x8*>(&hbuf[0][nd * S_H + 32 + quad * 8]);
        bf16x8 axs;
        if (quad == 0) {
            int node = node0 + nd;
            if (node >= NNODES) node = 0;
            axs = cvt8(x_stat + (size_t)node * STATF);
        } else {
            axs = zero8();
        }
        const f32x4 z4 = {0.f, 0.f, 0.f, 0.f};
        f32x4 aw;
        aw = __builtin_amdgcn_mfma_f32_16x16x32_bf16(a0, Bw0, z4, 0, 0, 0);
        aw = __builtin_amdgcn_mfma_f32_16x16x32_bf16(a1, Bw1, aw, 0, 0, 0);
        aw = __builtin_amdgcn_mfma_f32_16x16x32_bf16(axs, Bw2, aw, 0, 0, 0);
        #pragma unroll
        for (int r = 0; r < 4; ++r) {
            const int node = node0 + mt * 16 + quad * 4 + r;
            if (node < NNODES) t1[(size_t)node * HDIM + jg] = f2bf(aw[r]);
        }
    }
}

// ---------------------------------------------------------------------------
// CSR build phase 1: in-degree histogram (int atomics).
// ---------------------------------------------------------------------------
__global__ __launch_bounds__(256) void hist_kernel(
    const int* __restrict__ dstv, int* __restrict__ deg)
{
    const int e = blockIdx.x * 256 + threadIdx.x;
    if (e < NEDGES) atomicAdd(&deg[dstv[e]], 1);
}

// ---------------------------------------------------------------------------
// CSR build phase 2: exclusive scan of deg -> offs, cursor copy.
// ---------------------------------------------------------------------------
__global__ __launch_bounds__(1024) void scan_kernel(
    const int* __restrict__ deg, int* __restrict__ offs, int* __restrict__ cursor)
{
    __shared__ int wsum[16];
    const int tid = (int)threadIdx.x;
    const int lane = tid & 63;
    const int wid = tid >> 6;
    int carry = 0;

    for (int base = 0; base < NNODES; base += 1024) {
        const int idx = base + tid;
        const int v = (idx < NNODES) ? deg[idx] : 0;
        int incl = v;
        #pragma unroll
        for (int off = 1; off < 64; off <<= 1) {
            int t = __shfl_up(incl, off, 64);
            if (lane >= off) incl += t;
        }
        if (lane == 63) wsum[wid] = incl;
        __syncthreads();
        if (wid == 0 && lane < 16) {
            int s = wsum[lane];
            #pragma unroll
            for (int off = 1; off < 16; off <<= 1) {
                int t = __shfl_up(s, off, 16);
                if ((lane & 15) >= off) s += t;
            }
            wsum[lane] = s;
        }
        __syncthreads();
        const int wbase = (wid == 0) ? 0 : wsum[wid - 1];
        const int excl = carry + wbase + incl - v;
        if (idx < NNODES) { offs[idx] = excl; cursor[idx] = excl; }
        carry += wsum[15];
        __syncthreads();
    }
    if (tid == 0) offs[NNODES] = carry;
}

// ---------------------------------------------------------------------------
// CSR build phase 3: slot fill, XCD dst-range partitioned.
// blockIdx = chunk*8 + range; range r (= XCD via round-robin dispatch) only
// processes edges with dst in [r*6250, (r+1)*6250). All csr stores for a
// given line then come from ONE XCD's L2 -> ~16 stores/line coalesce ->
// writeback ~6.4MB instead of 100MB. Mapping wrong => slower, never wrong.
// ---------------------------------------------------------------------------
__global__ __launch_bounds__(256) void fill_kernel(
    const int* __restrict__ srcv, const int* __restrict__ dstv,
    const float* __restrict__ ew, int* __restrict__ cursor,
    unsigned* __restrict__ csr)
{
    const int range = (int)blockIdx.x & 7;
    const int chunk = (int)blockIdx.x >> 3;
    const int e = chunk * 256 + (int)threadIdx.x;
    if (e >= NEDGES) return;
    const int d = dstv[e];
    const int lo = range * (NNODES / 8);
    const int hi = (range == 7) ? NNODES : lo + (NNODES / 8);
    if (d < lo || d >= hi) return;
    const int pos = atomicAdd(&cursor[d], 1);
    csr[pos] = (unsigned)srcv[e] | ((unsigned)f2bf(ew[e]) << 16);
}

// ---------------------------------------------------------------------------
// Gather-reduce per dst node: one wave per node, lane = feature.
// ---------------------------------------------------------------------------
__global__ __launch_bounds__(256) void gather_kernel(
    const unsigned short* __restrict__ tsrc, const int* __restrict__ offs,
    const unsigned* __restrict__ csr, float* __restrict__ agg)
{
    const int node = blockIdx.x * 4 + (threadIdx.x >> 6);
    const int lane = threadIdx.x & 63;
    if (node >= NNODES) return;
    const int beg = offs[node];
    const int end = offs[node + 1];
    float acc = 0.f;
    int i = beg;
    for (; i + 4 <= end; i += 4) {   // 4 independent gathers in flight
        const unsigned p0 = csr[i],     p1 = csr[i + 1];
        const unsigned p2 = csr[i + 2], p3 = csr[i + 3];
        const float v0 = bf2f(tsrc[(size_t)(p0 & 0xFFFFu) * HDIM + lane]);
        const float v1 = bf2f(tsrc[(size_t)(p1 & 0xFFFFu) * HDIM + lane]);
        const float v2 = bf2f(tsrc[(size_t)(p2 & 0xFFFFu) * HDIM + lane]);
        const float v3 = bf2f(tsrc[(size_t)(p3 & 0xFFFFu) * HDIM + lane]);
        acc += __uint_as_float(p0 & 0xFFFF0000u) * v0
             + __uint_as_float(p1 & 0xFFFF0000u) * v1
             + __uint_as_float(p2 & 0xFFFF0000u) * v2
             + __uint_as_float(p3 & 0xFFFF0000u) * v3;
    }
    for (; i < end; ++i) {
        const unsigned p = csr[i];
        acc += __uint_as_float(p & 0xFFFF0000u)
             * bf2f(tsrc[(size_t)(p & 0xFFFFu) * HDIM + lane]);
    }
    agg[(size_t)node * HDIM + lane] = acc;
}

// ---------------------------------------------------------------------------
// h = relu(agg + bias); out = h @ W (64x64), bf16 out. 4 threads/node.
// ---------------------------------------------------------------------------
__global__ __launch_bounds__(256) void transform_kernel(
    const float* __restrict__ agg, const float* __restrict__ bias,
    const float* __restrict__ W, unsigned short* __restrict__ out)
{
    const int nl = threadIdx.x & 63;
    const int p = __builtin_amdgcn_readfirstlane((int)(threadIdx.x >> 6));
    const int node = blockIdx.x * 64 + nl;
    if (node >= NNODES) return;

    float in[HDIM];
    const float* arow = agg + (size_t)node * HDIM;
    #pragma unroll
    for (int c = 0; c < 16; ++c) {
        float4 v = *reinterpret_cast<const float4*>(arow + c * 4);
        in[c*4+0] = fmaxf(v.x + bias[c*4+0], 0.f);
        in[c*4+1] = fmaxf(v.y + bias[c*4+1], 0.f);
        in[c*4+2] = fmaxf(v.z + bias[c*4+2], 0.f);
        in[c*4+3] = fmaxf(v.w + bias[c*4+3], 0.f);
    }
    float acc[16];
    #pragma unroll
    for (int jj = 0; jj < 16; ++jj) acc[jj] = 0.f;
    #pragma unroll
    for (int k = 0; k < HDIM; ++k) {
        #pragma unroll
        for (int jj = 0; jj < 16; ++jj)
            acc[jj] += in[k] * W[k * HDIM + p * 16 + jj];
    }
    bf16x8 o0, o1;
    #pragma unroll
    for (int jj = 0; jj < 8; ++jj) {
        o0[jj] = (short)f2bf(acc[jj]);
        o1[jj] = (short)f2bf(acc[jj + 8]);
    }
    unsigned short* orow = out + (size_t)node * HDIM + p * 16;
    *reinterpret_cast<bf16x8*>(orow) = o0;
    *reinterpret_cast<bf16x8*>(orow + 8) = o1;
}

// ---------------------------------------------------------------------------
// Heads: h2 = relu(agg2 + b2); aqi = h2.Wa + ba; pm = h2.Wp + bp
// ---------------------------------------------------------------------------
__global__ __launch_bounds__(256) void head_kernel(
    const float* __restrict__ agg2, const float* __restrict__ b2,
    const float* __restrict__ Wa, const float* __restrict__ ba,
    const float* __restrict__ Wp, const float* __restrict__ bp,
    float* __restrict__ out)
{
    const int node = blockIdx.x * 256 + threadIdx.x;
    if (node >= NNODES) return;
    const float* arow = agg2 + (size_t)node * HDIM;
    float sa = 0.f, sp = 0.f;
    #pragma unroll
    for (int c = 0; c < 16; ++c) {
        float4 v = *reinterpret_cast<const float4*>(arow + c * 4);
        float h0 = fmaxf(v.x + b2[c*4+0], 0.f);
        float h1 = fmaxf(v.y + b2[c*4+1], 0.f);
        float h2 = fmaxf(v.z + b2[c*4+2], 0.f);
        float h3 = fmaxf(v.w + b2[c*4+3], 0.f);
        sa += h0 * Wa[c*4+0] + h1 * Wa[c*4+1] + h2 * Wa[c*4+2] + h3 * Wa[c*4+3];
        sp += h0 * Wp[c*4+0] + h1 * Wp[c*4+1] + h2 * Wp[c*4+2] + h3 * Wp[c*4+3];
    }
    out[node] = sa + ba[0];
    out[NNODES + node] = sp + bp[0];
}

extern "C" void kernel_launch(void* const* d_in, const int* in_sizes, int n_in,
                              void* d_out, int out_size, void* d_ws, size_t ws_size,
                              hipStream_t stream)
{
    const float* x_dyn  = (const float*)d_in[0];
    const float* x_stat = (const float*)d_in[1];
    const int*   eidx   = (const int*)  d_in[2];
    const float* ew     = (const float*)d_in[3];
    const float* Wih    = (const float*)d_in[4];
    const float* Whh    = (const float*)d_in[5];
    const float* bih    = (const float*)d_in[6];
    const float* bhh    = (const float*)d_in[7];
    const float* W1     = (const float*)d_in[8];
    const float* b1     = (const float*)d_in[9];
    const float* W2     = (const float*)d_in[10];
    const float* b2     = (const float*)d_in[11];
    const float* Wa     = (const float*)d_in[12];
    const float* ba     = (const float*)d_in[13];
    const float* Wp     = (const float*)d_in[14];
    const float* bp     = (const float*)d_in[15];

    const int* srcv = eidx;
    const int* dstv = eidx + NEDGES;

    // workspace layout (4B units)
    const size_t NH = (size_t)NNODES * HDIM;    // 3.2M elements
    float* ws   = (float*)d_ws;
    unsigned short* t1 = (unsigned short*)ws;                 // [NH] bf16
    unsigned short* t2 = (unsigned short*)(ws + NH / 2);      // [NH] bf16
    float* agg1 = ws + NH;            // [NH] fp32
    float* agg2 = ws + 2 * NH;        // [NH] fp32
    int*   deg    = (int*)(ws + 3 * NH);              // [NNODES]
    int*   offs   = deg + NNODES;                     // [NNODES+1]
    int*   cursor = offs + NNODES + 1;                // [NNODES]
    unsigned* csr = (unsigned*)(cursor + NNODES);     // [NEDGES] packed (src|w)

    dim3 blk(256);

    // ---- GRU + W1 (longest independent work first) ----
    gru_w1_kernel<<<dim3((NNODES + NB - 1) / NB), blk, 0, stream>>>(
        x_dyn, x_stat, Wih, Whh, bih, bhh, W1, t1);

    // ---- CSR build (once, reused by both layers) ----
    hipMemsetAsync(deg, 0, (size_t)NNODES * sizeof(int), stream);
    hist_kernel<<<dim3((NEDGES + 255) / 256), blk, 0, stream>>>(dstv, deg);
    scan_kernel<<<dim3(1), dim3(1024), 0, stream>>>(deg, offs, cursor);
    fill_kernel<<<dim3(((NEDGES + 255) / 256) * 8), blk, 0, stream>>>(
        srcv, dstv, ew, cursor, csr);

    // ---- layer 1 ----
    gather_kernel<<<dim3((NNODES + 3) / 4), blk, 0, stream>>>(t1, offs, csr, agg1);
    transform_kernel<<<dim3((NNODES + 63) / 64), blk, 0, stream>>>(agg1, b1, W2, t2);

    // ---- layer 2 ----
    gather_kernel<<<dim3((NNODES + 3) / 4), blk, 0, stream>>>(t2, offs, csr, agg2);
    head_kernel<<<dim3((NNODES + 255) / 256), blk, 0, stream>>>(
        agg2, b2, Wa, ba, Wp, bp, (float*)d_out);
}